// Round 4
// baseline (81.567 us; speedup 1.0000x reference)
//
#include <hip/hip_runtime.h>

#define T_TRIG 48
#define S_SPAN 128
#define NN (T_TRIG * S_SPAN)      // 6144 nodes
#define D 128                     // feature dim

typedef __attribute__((ext_vector_type(8))) short sh8;
typedef __attribute__((ext_vector_type(4))) float f32x4;
typedef __attribute__((ext_vector_type(4))) unsigned short us4;

__device__ inline unsigned short f2bf(float v) {
    unsigned u = __float_as_uint(v);
    unsigned r = u + 0x7FFFu + ((u >> 16) & 1u);   // RTNE
    return (unsigned short)(r >> 16);
}
__device__ inline float bf2f(unsigned short b) {
    return __uint_as_float(((unsigned)b) << 16);
}

// ---------------------------------------------------------------------------
// Prep: blocks 0-15 pack W1/W2 into MFMA B-fragment hi/lo bf16; blocks 16+
// split pe (fp32) into row-major bf16 hi/lo.
// W frag layout: frag[(ntile*4+kc)*64 + lane][i] , k = kc*32+(lane>>4)*8+i,
//                n = ntile*16 + (lane&15).
// ---------------------------------------------------------------------------
__global__ __launch_bounds__(256) void prep_kernel(
    const float* __restrict__ pe, const float* __restrict__ W1,
    const float* __restrict__ W2,
    unsigned short* __restrict__ x1h, unsigned short* __restrict__ x1l,
    unsigned short* __restrict__ w1h, unsigned short* __restrict__ w1l,
    unsigned short* __restrict__ w2h, unsigned short* __restrict__ w2l)
{
    const int b = blockIdx.x;
    const int t = threadIdx.x;
    if (b < 16) {
        const float* W = (b < 8) ? W1 : W2;
        unsigned short* wh = (b < 8) ? w1h : w2h;
        unsigned short* wl = (b < 8) ? w1l : w2l;
        const int nt = b & 7;
        const int kc = t >> 6;
        const int l = t & 63;
        const int n = nt * 16 + (l & 15);
        const int kb = kc * 32 + (l >> 4) * 8;
        unsigned short hb[8], lb[8];
        #pragma unroll
        for (int i = 0; i < 8; ++i) {
            float v = W[(kb + i) * D + n];
            unsigned short h = f2bf(v);
            hb[i] = h;
            lb[i] = f2bf(v - bf2f(h));
        }
        size_t base = ((size_t)(nt * 4 + kc) * 64 + l) * 8;
        #pragma unroll
        for (int i = 0; i < 8; ++i) { wh[base + i] = hb[i]; wl[base + i] = lb[i]; }
    } else {
        const int idx = (b - 16) * 256 + t;       // 8-elem chunk index
        const float* p = pe + (size_t)idx * 8;
        float4 v0 = *(const float4*)p;
        float4 v1 = *(const float4*)(p + 4);
        float xs[8] = {v0.x, v0.y, v0.z, v0.w, v1.x, v1.y, v1.z, v1.w};
        sh8 hv, lv;
        #pragma unroll
        for (int i = 0; i < 8; ++i) {
            unsigned short h = f2bf(xs[i]);
            hv[i] = (short)h;
            lv[i] = (short)f2bf(xs[i] - bf2f(h));
        }
        ((sh8*)x1h)[idx] = hv;
        ((sh8*)x1l)[idx] = lv;
    }
}

// ---------------------------------------------------------------------------
// MFMA GEMM  H = X @ W, split-bf16 (3 MFMAs/chunk), fused attention scalars.
// 768 blocks x 256 thr (4 waves). Wave tile = 16x16.
// block: mt = bid>>1 (rows mt*16..+15), nq = bid&1; wave w -> ntile nq*4+w.
// ---------------------------------------------------------------------------
__global__ __launch_bounds__(256) void gemm_mfma_kernel(
    const unsigned short* __restrict__ Xh, const unsigned short* __restrict__ Xl,
    const unsigned short* __restrict__ Wh, const unsigned short* __restrict__ Wl,
    const float* __restrict__ att_s, const float* __restrict__ att_d,
    float* __restrict__ H, float* __restrict__ asrc, float* __restrict__ adst)
{
    __shared__ float ps_part[4][16], pd_part[4][16];

    const int t = threadIdx.x;
    const int w = t >> 6;
    const int l = t & 63;
    const int mt = blockIdx.x >> 1;
    const int nq = blockIdx.x & 1;
    const int nt = nq * 4 + w;
    const int c = l & 15;
    const int kg = l >> 4;
    const int row0 = mt * 16;

    const sh8* Xh8 = (const sh8*)Xh;
    const sh8* Xl8 = (const sh8*)Xl;
    const sh8* Wh8 = (const sh8*)Wh;
    const sh8* Wl8 = (const sh8*)Wl;

    f32x4 acc = {0, 0, 0, 0};
    #pragma unroll
    for (int kc = 0; kc < 4; ++kc) {
        const int xi = (row0 + c) * 16 + kc * 4 + kg;
        sh8 ah = Xh8[xi];
        sh8 al = Xl8[xi];
        sh8 bh = Wh8[(nt * 4 + kc) * 64 + l];
        sh8 bl = Wl8[(nt * 4 + kc) * 64 + l];
        acc = __builtin_amdgcn_mfma_f32_16x16x32_bf16(ah, bh, acc, 0, 0, 0);
        acc = __builtin_amdgcn_mfma_f32_16x16x32_bf16(al, bh, acc, 0, 0, 0);
        acc = __builtin_amdgcn_mfma_f32_16x16x32_bf16(ah, bl, acc, 0, 0, 0);
    }

    // store H: D layout col=c, row=kg*4+i
    #pragma unroll
    for (int i = 0; i < 4; ++i)
        H[(size_t)(row0 + kg * 4 + i) * D + nt * 16 + c] = acc[i];

    // attention partials for this ntile (head nt>>1, half nt&1)
    const int dim = (nt >> 1) * 32 + (nt & 1) * 16 + c;
    const float asv = att_s[dim];
    const float adv = att_d[dim];
    #pragma unroll
    for (int i = 0; i < 4; ++i) {
        float ps = acc[i] * asv;
        float pd = acc[i] * adv;
        ps += __shfl_xor(ps, 1); pd += __shfl_xor(pd, 1);
        ps += __shfl_xor(ps, 2); pd += __shfl_xor(pd, 2);
        ps += __shfl_xor(ps, 4); pd += __shfl_xor(pd, 4);
        ps += __shfl_xor(ps, 8); pd += __shfl_xor(pd, 8);
        if (c == 0) {
            ps_part[w][kg * 4 + i] = ps;
            pd_part[w][kg * 4 + i] = pd;
        }
    }
    __syncthreads();
    if (t < 32) {
        const int row = t & 15;
        const int hh = t >> 4;               // 0,1 within block
        const int head = nq * 2 + hh;
        asrc[(row0 + row) * 4 + head] = ps_part[2 * hh][row] + ps_part[2 * hh + 1][row];
        adst[(row0 + row) * 4 + head] = pd_part[2 * hh][row] + pd_part[2 * hh + 1][row];
    }
}

// ---------------------------------------------------------------------------
// Row aggregation: block per (row r, head h) = 192 blocks, 256 threads.
// ---------------------------------------------------------------------------
__global__ __launch_bounds__(256) void row_agg_kernel(
    const float* __restrict__ H, const float* __restrict__ asrc,
    const float* __restrict__ adst, float* __restrict__ num_row,
    float* __restrict__ den_row)
{
    __shared__ float sh_h[S_SPAN][32];
    __shared__ float sh_as[S_SPAN];
    const int tid = threadIdx.x;
    const int r = blockIdx.x >> 2;
    const int h = blockIdx.x & 3;
    const int base = r * S_SPAN;

    #pragma unroll
    for (int it = 0; it < 4; ++it) {
        int chunk = tid + it * 256;
        int cp = chunk >> 3, fc = chunk & 7;
        *(float4*)&sh_h[cp][fc * 4] =
            *(const float4*)&H[(size_t)(base + cp) * D + h * 32 + fc * 4];
    }
    if (tid < S_SPAN) sh_as[tid] = asrc[(base + tid) * 4 + h];
    __syncthreads();

    const int fg = tid & 3;
    const int cth = tid >> 2;
    const float ad0 = adst[(base + cth) * 4 + h];
    const float ad1 = adst[(base + cth + 64) * 4 + h];
    float4 n00 = {0,0,0,0}, n01 = {0,0,0,0}, n10 = {0,0,0,0}, n11 = {0,0,0,0};
    float den0 = 0.f, den1 = 0.f;

    #pragma unroll 2
    for (int cp = 0; cp < S_SPAN; ++cp) {
        float a = sh_as[cp];
        float4 h0 = *(float4*)&sh_h[cp][fg * 8];
        float4 h1 = *(float4*)&sh_h[cp][fg * 8 + 4];
        float e0 = a + ad0; e0 = fmaxf(e0, 0.2f * e0);
        float e1 = a + ad1; e1 = fmaxf(e1, 0.2f * e1);
        float w0 = __expf(e0);
        float w1 = __expf(e1);
        den0 += w0; den1 += w1;
        n00.x = fmaf(w0, h0.x, n00.x); n00.y = fmaf(w0, h0.y, n00.y);
        n00.z = fmaf(w0, h0.z, n00.z); n00.w = fmaf(w0, h0.w, n00.w);
        n01.x = fmaf(w0, h1.x, n01.x); n01.y = fmaf(w0, h1.y, n01.y);
        n01.z = fmaf(w0, h1.z, n01.z); n01.w = fmaf(w0, h1.w, n01.w);
        n10.x = fmaf(w1, h0.x, n10.x); n10.y = fmaf(w1, h0.y, n10.y);
        n10.z = fmaf(w1, h0.z, n10.z); n10.w = fmaf(w1, h0.w, n10.w);
        n11.x = fmaf(w1, h1.x, n11.x); n11.y = fmaf(w1, h1.y, n11.y);
        n11.z = fmaf(w1, h1.z, n11.z); n11.w = fmaf(w1, h1.w, n11.w);
    }

    const int n0 = base + cth, n1 = n0 + 64;
    *(float4*)&num_row[(size_t)n0 * D + h * 32 + fg * 8]     = n00;
    *(float4*)&num_row[(size_t)n0 * D + h * 32 + fg * 8 + 4] = n01;
    *(float4*)&num_row[(size_t)n1 * D + h * 32 + fg * 8]     = n10;
    *(float4*)&num_row[(size_t)n1 * D + h * 32 + fg * 8 + 4] = n11;
    if (fg == 0) {
        den_row[n0 * 4 + h] = den0;
        den_row[n1 * 4 + h] = den1;
    }
}

// ---------------------------------------------------------------------------
// Column aggregation + finalize. If xh != nullptr, writes split-bf16 hi/lo
// (next layer's GEMM input); else writes fp32 out.
// ---------------------------------------------------------------------------
__global__ __launch_bounds__(256) void col_agg_kernel(
    const float* __restrict__ H, const float* __restrict__ asrc,
    const float* __restrict__ adst, const float* __restrict__ num_row,
    const float* __restrict__ den_row, const float* __restrict__ bias,
    float* __restrict__ out, unsigned short* __restrict__ xh,
    unsigned short* __restrict__ xl)
{
    __shared__ float sh_h[T_TRIG][D];
    __shared__ float sh_as[4][T_TRIG];
    const int c = blockIdx.x;
    const int tid = threadIdx.x;

    #pragma unroll
    for (int it = 0; it < 6; ++it) {
        int chunk = tid + it * 256;
        int t = chunk >> 5, fc = chunk & 31;
        *(float4*)&sh_h[t][fc * 4] =
            *(const float4*)&H[(size_t)(t * S_SPAN + c) * D + fc * 4];
    }
    if (tid < 4 * T_TRIG) {
        int hh = tid / T_TRIG, t = tid - hh * T_TRIG;
        sh_as[hh][t] = asrc[(t * S_SPAN + c) * 4 + hh];
    }
    __syncthreads();

    const int f4g = tid & 31;
    const int tg = tid >> 5;
    const int head = f4g >> 3;

    float4 num[6];
    float den[6], ad[6];
    #pragma unroll
    for (int dd = 0; dd < 6; ++dd) {
        num[dd] = {0,0,0,0};
        den[dd] = 0.f;
        ad[dd] = adst[((tg * 6 + dd) * S_SPAN + c) * 4 + head];
    }

    for (int tp = 0; tp < T_TRIG; ++tp) {
        float a = sh_as[head][tp];
        float4 hv = *(float4*)&sh_h[tp][f4g * 4];
        #pragma unroll
        for (int dd = 0; dd < 6; ++dd) {
            float e = a + ad[dd];
            e = fmaxf(e, 0.2f * e);
            float w = __expf(e);
            w = (tp == tg * 6 + dd) ? 0.f : w;
            den[dd] += w;
            num[dd].x = fmaf(w, hv.x, num[dd].x);
            num[dd].y = fmaf(w, hv.y, num[dd].y);
            num[dd].z = fmaf(w, hv.z, num[dd].z);
            num[dd].w = fmaf(w, hv.w, num[dd].w);
        }
    }

    const float4 b4 = *(const float4*)&bias[f4g * 4];
    #pragma unroll
    for (int dd = 0; dd < 6; ++dd) {
        int n = (tg * 6 + dd) * S_SPAN + c;
        float4 nr = *(const float4*)&num_row[(size_t)n * D + f4g * 4];
        float dr = den_row[n * 4 + head];
        float inv = 1.f / (dr + den[dd]);
        float o[4];
        o[0] = (nr.x + num[dd].x) * inv + b4.x;
        o[1] = (nr.y + num[dd].y) * inv + b4.y;
        o[2] = (nr.z + num[dd].z) * inv + b4.z;
        o[3] = (nr.w + num[dd].w) * inv + b4.w;
        #pragma unroll
        for (int q = 0; q < 4; ++q)
            o[q] = o[q] > 0.f ? o[q] : (__expf(o[q]) - 1.f);
        if (xh) {
            us4 hv4, lv4;
            #pragma unroll
            for (int q = 0; q < 4; ++q) {
                unsigned short hq = f2bf(o[q]);
                hv4[q] = hq;
                lv4[q] = f2bf(o[q] - bf2f(hq));
            }
            *(us4*)&xh[(size_t)n * D + f4g * 4] = hv4;
            *(us4*)&xl[(size_t)n * D + f4g * 4] = lv4;
        } else {
            float4 o4 = {o[0], o[1], o[2], o[3]};
            *(float4*)&out[(size_t)n * D + f4g * 4] = o4;
        }
    }
}

// ---------------------------------------------------------------------------
extern "C" void kernel_launch(void* const* d_in, const int* in_sizes, int n_in,
                              void* d_out, int out_size, void* d_ws, size_t ws_size,
                              hipStream_t stream)
{
    const float* pe  = (const float*)d_in[0];
    const float* W1  = (const float*)d_in[1];
    const float* as1 = (const float*)d_in[2];
    const float* ad1 = (const float*)d_in[3];
    const float* b1  = (const float*)d_in[4];
    const float* W2  = (const float*)d_in[5];
    const float* as2 = (const float*)d_in[6];
    const float* ad2 = (const float*)d_in[7];
    const float* b2  = (const float*)d_in[8];
    float* out = (float*)d_out;

    char* ws = (char*)d_ws;
    float* H     = (float*)ws;                                   // NN*D f32
    float* numr  = H + (size_t)NN * D;                           // NN*D f32
    float* asrcb = numr + (size_t)NN * D;                        // NN*4
    float* adstb = asrcb + (size_t)NN * 4;
    float* denb  = adstb + (size_t)NN * 4;
    unsigned short* x1h = (unsigned short*)(denb + (size_t)NN * 4);
    unsigned short* x1l = x1h + (size_t)NN * D;
    unsigned short* x2h = x1l + (size_t)NN * D;
    unsigned short* x2l = x2h + (size_t)NN * D;
    unsigned short* w1h = x2l + (size_t)NN * D;
    unsigned short* w1l = w1h + D * D;
    unsigned short* w2h = w1l + D * D;
    unsigned short* w2l = w2h + D * D;

    prep_kernel<<<dim3(16 + NN * D / 8 / 256), dim3(256), 0, stream>>>(
        pe, W1, W2, x1h, x1l, w1h, w1l, w2h, w2l);

    // layer 1
    gemm_mfma_kernel<<<dim3(NN / 16 * 2), dim3(256), 0, stream>>>(
        x1h, x1l, w1h, w1l, as1, ad1, H, asrcb, adstb);
    row_agg_kernel<<<dim3(T_TRIG * 4), dim3(256), 0, stream>>>(H, asrcb, adstb, numr, denb);
    col_agg_kernel<<<dim3(S_SPAN), dim3(256), 0, stream>>>(
        H, asrcb, adstb, numr, denb, b1, nullptr, x2h, x2l);
    // layer 2
    gemm_mfma_kernel<<<dim3(NN / 16 * 2), dim3(256), 0, stream>>>(
        x2h, x2l, w2h, w2l, as2, ad2, H, asrcb, adstb);
    row_agg_kernel<<<dim3(T_TRIG * 4), dim3(256), 0, stream>>>(H, asrcb, adstb, numr, denb);
    col_agg_kernel<<<dim3(S_SPAN), dim3(256), 0, stream>>>(
        H, asrcb, adstb, numr, denb, b2, out, nullptr, nullptr);
}